// Round 1
// baseline (67.679 us; speedup 1.0000x reference)
//
#include <hip/hip_runtime.h>
#include <hip/hip_bf16.h>

// SeesawLoss forward, N=32768 rows, C=1203 classes (+2 binary logits).
// Pipeline: zero hist -> int-atomic histogram -> log(count) table ->
// per-row wave kernel (row cached in 19 VGPRs/lane, read HBM once) ->
// deterministic tree reduction. No float atomics (determinism).

#define C_CLS   1203
#define ROW_LEN 1205          // C + 2
#define NBINS   1204          // C + 1
#define NSEG    19            // ceil(1203 / 64)
#define NEG_HUGE (-3.402823466e38f)
#define LOG_EPS  (-4.605170185988091f)   // ln(0.01)
#define P_POW    0.8f
#define Q_POW    2.0f

__global__ void hist_k(const int* __restrict__ labels, unsigned* __restrict__ cum, int N) {
    int i = blockIdx.x * blockDim.x + threadIdx.x;
    if (i < N) {
        int l = labels[i];
        if (l >= 0 && l < NBINS) atomicAdd(&cum[l], 1u);
    }
}

__global__ void logc_k(const unsigned* __restrict__ cum, float* __restrict__ logc) {
    int j = blockIdx.x * blockDim.x + threadIdx.x;
    if (j < NBINS) {
        float c = fmaxf((float)cum[j], 1.0f);
        logc[j] = __logf(c);
    }
}

// One wave (64 lanes) per row; 4 waves (256 threads) per block.
__launch_bounds__(256)
__global__ void seesaw_row_k(const float* __restrict__ cls,
                             const int* __restrict__ labels,
                             const float* __restrict__ lweights,
                             const float* __restrict__ logc,
                             float* __restrict__ blocksums,
                             int N) {
    const int lane = threadIdx.x & 63;
    const int wv   = threadIdx.x >> 6;
    const int n    = blockIdx.x * 4 + wv;
    const bool act = (n < N);

    const float* row = cls + (size_t)(act ? n : 0) * ROW_LEN;
    const int label  = act ? labels[act ? n : 0] : 0;

    // ---- load row into registers, track csc[label] ----
    float v[NSEG];
    float labval = NEG_HUGE;
    #pragma unroll
    for (int i = 0; i < NSEG; ++i) {
        int idx = lane + 64 * i;
        float x = (idx < C_CLS) ? row[idx] : NEG_HUGE;
        v[i] = x;
        if (idx == label) labval = x;
    }

    // ---- wave max of csc, and broadcast csc[label] ----
    float m = NEG_HUGE;
    #pragma unroll
    for (int i = 0; i < NSEG; ++i) m = fmaxf(m, v[i]);
    #pragma unroll
    for (int o = 32; o > 0; o >>= 1) {
        m      = fmaxf(m,      __shfl_xor(m,      o, 64));
        labval = fmaxf(labval, __shfl_xor(labval, o, 64));
    }

    // ---- softmax log-denominator L = m + log(sum exp(csc - m)) ----
    float s = 0.0f;
    #pragma unroll
    for (int i = 0; i < NSEG; ++i) s += __expf(v[i] - m);
    #pragma unroll
    for (int o = 32; o > 0; o >>= 1) s += __shfl_xor(s, o, 64);
    const float L = m + __logf(s);

    const float log_sm = fmaxf(labval - L, LOG_EPS);   // log(max(self_score, EPS))
    const float lclog  = logc[label];                  // scalar (L1-resident table)

    // ---- adjusted logits (overwrite v[]), excluding label ----
    #pragma unroll
    for (int i = 0; i < NSEG; ++i) {
        int idx = lane + 64 * i;
        float a = NEG_HUGE;
        if (idx < C_CLS && idx != label) {
            float dl   = logc[idx] - lclog;             // ln(cum_j / cum_label)
            float mit  = (dl < 0.0f) ? P_POW * dl : 0.0f;
            float ls   = v[i] - L;                      // log score_j
            float comp = (ls > log_sm) ? Q_POW * (ls - log_sm) : 0.0f;
            a = v[i] + mit + comp;
        }
        v[i] = a;
    }

    // ---- logsumexp over j != label ----
    float A = NEG_HUGE;
    #pragma unroll
    for (int i = 0; i < NSEG; ++i) A = fmaxf(A, v[i]);
    #pragma unroll
    for (int o = 32; o > 0; o >>= 1) A = fmaxf(A, __shfl_xor(A, o, 64));

    float T = 0.0f;
    #pragma unroll
    for (int i = 0; i < NSEG; ++i) T += __expf(v[i] - A);
    #pragma unroll
    for (int o = 32; o > 0; o >>= 1) T += __shfl_xor(T, o, 64);
    const float neg_lse = A + __logf(T);

    // ---- per-row tail on lane 0 ----
    float contrib = 0.0f;
    if (lane == 0 && act) {
        float x  = neg_lse - labval;
        float rl = (x > 0.0f) ? (x + log1pf(__expf(-x))) : log1pf(__expf(x));

        // binary head: ce = lse(csb0, csb1) - csb[b], b = (label == C)
        float c0 = row[C_CLS], c1 = row[C_CLS + 1];
        float mm = fmaxf(c0, c1);
        float lseb = mm + __logf(__expf(c0 - mm) + __expf(c1 - mm));
        int   bl = (label == C_CLS) ? 1 : 0;
        float ce = lseb - (bl ? c1 : c0);

        float w = lweights[n];
        // reference semantics: class loss selected only where mask == 1.0
        float rlw = (w == 1.0f) ? rl : 0.0f;
        contrib = rlw + ce * w;
    }

    __shared__ float bs[4];
    if (lane == 0) bs[wv] = contrib;
    __syncthreads();
    if (threadIdx.x == 0)
        blocksums[blockIdx.x] = bs[0] + bs[1] + bs[2] + bs[3];
}

__global__ void reduce_k(const float* __restrict__ bsums, int nb,
                         const int* __restrict__ avg_raw,
                         float* __restrict__ out) {
    float s = 0.0f;
    for (int i = threadIdx.x; i < nb; i += 256) s += bsums[i];
    #pragma unroll
    for (int o = 32; o > 0; o >>= 1) s += __shfl_xor(s, o, 64);

    __shared__ float ws4[4];
    int lane = threadIdx.x & 63, wv = threadIdx.x >> 6;
    if (lane == 0) ws4[wv] = s;
    __syncthreads();
    if (threadIdx.x == 0) {
        float t = ws4[0] + ws4[1] + ws4[2] + ws4[3];
        int ai = avg_raw[0];
        float af;
        if (ai > 0 && ai < (1 << 26)) {
            af = (float)ai;              // stored as integer
        } else {
            union { int i; float f; } u; // stored as float bits
            u.i = ai;
            af = u.f;
        }
        out[0] = t / af;
    }
}

extern "C" void kernel_launch(void* const* d_in, const int* in_sizes, int n_in,
                              void* d_out, int out_size, void* d_ws, size_t ws_size,
                              hipStream_t stream) {
    const float* cls    = (const float*)d_in[0];
    const int*   labels = (const int*)d_in[1];
    const float* lw     = (const float*)d_in[2];
    const int*   avgp   = (const int*)d_in[3];
    float*       out    = (float*)d_out;

    const int N = in_sizes[1];

    // ws layout: [ unsigned cum[NBINS] | float logc[NBINS] | float blocksums[nblocks] ]
    unsigned* cum   = (unsigned*)d_ws;
    float*    logc  = (float*)d_ws + NBINS;
    float*    bsums = (float*)d_ws + 2 * NBINS;

    const int nblocks = (N + 3) / 4;

    hipMemsetAsync(d_ws, 0, NBINS * sizeof(unsigned), stream);
    hist_k<<<(N + 255) / 256, 256, 0, stream>>>(labels, cum, N);
    logc_k<<<(NBINS + 255) / 256, 256, 0, stream>>>(cum, logc);
    seesaw_row_k<<<nblocks, 256, 0, stream>>>(cls, labels, lw, logc, bsums, N);
    reduce_k<<<1, 256, 0, stream>>>(bsums, nblocks, avgp, out);
}

// Round 2
// 64.083 us; speedup vs baseline: 1.0561x; 1.0561x over previous
//
#include <hip/hip_runtime.h>
#include <hip/hip_bf16.h>

// SeesawLoss forward, N=32768 rows, C=1203 classes (+2 binary logits).
// Round 2: float4-vectorized row loads (alignment-classed prefix + 5 aligned
// dwordx4 per lane), binary logits extracted via the max shuffle tree
// (no dependent scalar tail loads), logc gathers hoisted above the trees.
// No float atomics anywhere (determinism).

#define C_CLS   1203
#define ROW_LEN 1205          // C + 2
#define NBINS   1204          // C + 1
#define NEG_HUGE (-3.402823466e38f)
#define LOG_EPS  (-4.605170185988091f)   // ln(0.01)
#define P_POW    0.8f
#define Q_POW    2.0f

__global__ void hist_k(const int* __restrict__ labels, unsigned* __restrict__ cum, int N) {
    int i = blockIdx.x * blockDim.x + threadIdx.x;
    if (i < N) {
        int l = labels[i];
        if (l >= 0 && l < NBINS) atomicAdd(&cum[l], 1u);
    }
}

__global__ void logc_k(const unsigned* __restrict__ cum, float* __restrict__ logc) {
    int j = blockIdx.x * blockDim.x + threadIdx.x;
    if (j < NBINS) {
        float c = fmaxf((float)cum[j], 1.0f);
        logc[j] = __logf(c);
    }
}

// One wave (64 lanes) per row; 4 waves (256 threads) per block.
// Row layout per lane: prefix element [lane] if lane<k (k = (-n)&3 aligns to
// 16B), then 5 float4 segments at element k + 256*i + 4*lane.
__launch_bounds__(256)
__global__ void seesaw_row_k(const float* __restrict__ cls,
                             const int* __restrict__ labels,
                             const float* __restrict__ lweights,
                             const float* __restrict__ logc,
                             float* __restrict__ blocksums,
                             int N) {
    const int lane = threadIdx.x & 63;
    const int wv   = threadIdx.x >> 6;
    const int n    = blockIdx.x * 4 + wv;
    const bool act = (n < N);
    const int nn   = act ? n : 0;

    const size_t base = (size_t)nn * ROW_LEN;
    const float* row  = cls + base;
    const int   label = labels[nn];
    const float w     = lweights[nn];

    const int k = (-nn) & 3;             // 1205 % 4 == 1, so base%4 == nn%4

    // ---- vectorized row load: 5 x dwordx4 + tiny prefix ----
    const float4* vp = (const float4*)(row + k);   // 16B aligned
    float4 q[5];
    #pragma unroll
    for (int i = 0; i < 4; ++i) q[i] = vp[(size_t)i * 64 + lane];
    {
        // segment 4 partially exceeds the row; guard (stays within this row)
        int b4 = k + 1024 + 4 * lane;
        float4 t = make_float4(NEG_HUGE, NEG_HUGE, NEG_HUGE, NEG_HUGE);
        if (b4 + 3 <= ROW_LEN - 1) {
            t = vp[(size_t)256 + lane];
        } else {
            if (b4     <= ROW_LEN - 1) t.x = row[b4];
            if (b4 + 1 <= ROW_LEN - 1) t.y = row[b4 + 1];
            if (b4 + 2 <= ROW_LEN - 1) t.z = row[b4 + 2];
        }
        q[4] = t;
    }
    const float pv = (lane < k) ? row[lane] : NEG_HUGE;

    // ---- hoisted logc gathers (table is ~4.8 KB, L1-resident) ----
    const float lcl = logc[label];
    float lgp = (lane < k) ? logc[lane] : 0.0f;
    float4 lg[5];
    #pragma unroll
    for (int i = 0; i < 5; ++i) {
        int b = k + 256 * i + 4 * lane;
        float4 t = make_float4(0.f, 0.f, 0.f, 0.f);
        if (b     < NBINS) t.x = logc[b];
        if (b + 1 < NBINS) t.y = logc[b + 1];
        if (b + 2 < NBINS) t.z = logc[b + 2];
        if (b + 3 < NBINS) t.w = logc[b + 3];
        lg[i] = t;
    }

    // ---- pass A: capture label/binary values, mask non-classes, lane max ----
    float m = NEG_HUGE, labv = NEG_HUGE, c0v = NEG_HUGE, c1v = NEG_HUGE;
    if (lane < k) {                       // prefix idx = lane < 3, always a class
        if (lane == label) labv = pv;
        m = fmaxf(m, pv);
    }
    #pragma unroll
    for (int i = 0; i < 5; ++i) {
        int b = k + 256 * i + 4 * lane;
        float vv[4] = {q[i].x, q[i].y, q[i].z, q[i].w};
        #pragma unroll
        for (int j = 0; j < 4; ++j) {
            int idx = b + j;
            float x = vv[j];
            if (idx == label)      labv = x;
            if (idx == C_CLS)      c0v  = x;
            if (idx == C_CLS + 1)  c1v  = x;
            x = (idx < C_CLS) ? x : NEG_HUGE;
            vv[j] = x;
            m = fmaxf(m, x);
        }
        q[i].x = vv[0]; q[i].y = vv[1]; q[i].z = vv[2]; q[i].w = vv[3];
    }

    // ---- tree 1: max + broadcasts of labval / binary logits ----
    #pragma unroll
    for (int o = 32; o > 0; o >>= 1) {
        m    = fmaxf(m,    __shfl_xor(m,    o, 64));
        labv = fmaxf(labv, __shfl_xor(labv, o, 64));
        c0v  = fmaxf(c0v,  __shfl_xor(c0v,  o, 64));
        c1v  = fmaxf(c1v,  __shfl_xor(c1v,  o, 64));
    }

    // ---- pass B: softmax log-denominator ----
    float s = __expf(pv - m);             // lane>=k: exp(NEG_HUGE-m) == 0
    #pragma unroll
    for (int i = 0; i < 5; ++i)
        s += __expf(q[i].x - m) + __expf(q[i].y - m)
           + __expf(q[i].z - m) + __expf(q[i].w - m);
    #pragma unroll
    for (int o = 32; o > 0; o >>= 1) s += __shfl_xor(s, o, 64);
    const float L      = m + __logf(s);
    const float log_sm = fmaxf(labv - L, LOG_EPS);   // log(max(self_score, EPS))

    // ---- pass C: adjusted logits (exclude label), lane max ----
    auto adj1 = [&](float x, float lgv, int idx) -> float {
        float a = x + P_POW * fminf(lgv - lcl, 0.0f)
                    + Q_POW * fmaxf((x - L) - log_sm, 0.0f);
        return (idx < C_CLS && idx != label) ? a : NEG_HUGE;
    };
    float ap = (lane < k) ? adj1(pv, lgp, lane) : NEG_HUGE;
    float A = ap;
    #pragma unroll
    for (int i = 0; i < 5; ++i) {
        int b = k + 256 * i + 4 * lane;
        q[i].x = adj1(q[i].x, lg[i].x, b);
        q[i].y = adj1(q[i].y, lg[i].y, b + 1);
        q[i].z = adj1(q[i].z, lg[i].z, b + 2);
        q[i].w = adj1(q[i].w, lg[i].w, b + 3);
        A = fmaxf(A, fmaxf(fmaxf(q[i].x, q[i].y), fmaxf(q[i].z, q[i].w)));
    }
    #pragma unroll
    for (int o = 32; o > 0; o >>= 1) A = fmaxf(A, __shfl_xor(A, o, 64));

    // ---- pass D: logsumexp over j != label ----
    float T = __expf(ap - A);
    #pragma unroll
    for (int i = 0; i < 5; ++i)
        T += __expf(q[i].x - A) + __expf(q[i].y - A)
           + __expf(q[i].z - A) + __expf(q[i].w - A);
    #pragma unroll
    for (int o = 32; o > 0; o >>= 1) T += __shfl_xor(T, o, 64);
    const float neg_lse = A + __logf(T);

    // ---- per-row tail on lane 0 (all values already in registers) ----
    float contrib = 0.0f;
    if (lane == 0 && act) {
        float xx = neg_lse - labv;        // pos_lse = -csc[label], inv_pos_log = 0
        float rl = (xx > 0.0f) ? (xx + log1pf(__expf(-xx))) : log1pf(__expf(xx));

        float mm   = fmaxf(c0v, c1v);
        float lseb = mm + __logf(__expf(c0v - mm) + __expf(c1v - mm));
        bool  bl   = (label == C_CLS);
        float ce   = lseb - (bl ? c1v : c0v);

        float rlw = (w == 1.0f) ? rl : 0.0f;  // reference: pos_mask == 1.0 select
        contrib = rlw + ce * w;
    }

    __shared__ float bs[4];
    if (lane == 0) bs[wv] = contrib;
    __syncthreads();
    if (threadIdx.x == 0)
        blocksums[blockIdx.x] = bs[0] + bs[1] + bs[2] + bs[3];
}

__global__ void reduce_k(const float* __restrict__ bsums, int nb,
                         const int* __restrict__ avg_raw,
                         float* __restrict__ out) {
    float s = 0.0f;
    for (int i = threadIdx.x; i < nb; i += 256) s += bsums[i];
    #pragma unroll
    for (int o = 32; o > 0; o >>= 1) s += __shfl_xor(s, o, 64);

    __shared__ float ws4[4];
    int lane = threadIdx.x & 63, wv = threadIdx.x >> 6;
    if (lane == 0) ws4[wv] = s;
    __syncthreads();
    if (threadIdx.x == 0) {
        float t = ws4[0] + ws4[1] + ws4[2] + ws4[3];
        int ai = avg_raw[0];
        float af;
        if (ai > 0 && ai < (1 << 26)) {
            af = (float)ai;              // stored as integer
        } else {
            union { int i; float f; } u; // stored as float bits
            u.i = ai;
            af = u.f;
        }
        out[0] = t / af;
    }
}

extern "C" void kernel_launch(void* const* d_in, const int* in_sizes, int n_in,
                              void* d_out, int out_size, void* d_ws, size_t ws_size,
                              hipStream_t stream) {
    const float* cls    = (const float*)d_in[0];
    const int*   labels = (const int*)d_in[1];
    const float* lw     = (const float*)d_in[2];
    const int*   avgp   = (const int*)d_in[3];
    float*       out    = (float*)d_out;

    const int N = in_sizes[1];

    // ws layout: [ unsigned cum[NBINS] | float logc[NBINS] | float blocksums[nblocks] ]
    unsigned* cum   = (unsigned*)d_ws;
    float*    logc  = (float*)d_ws + NBINS;
    float*    bsums = (float*)d_ws + 2 * NBINS;

    const int nblocks = (N + 3) / 4;

    hipMemsetAsync(d_ws, 0, NBINS * sizeof(unsigned), stream);
    hist_k<<<(N + 255) / 256, 256, 0, stream>>>(labels, cum, N);
    logc_k<<<(NBINS + 255) / 256, 256, 0, stream>>>(cum, logc);
    seesaw_row_k<<<nblocks, 256, 0, stream>>>(cls, labels, lw, logc, bsums, N);
    reduce_k<<<1, 256, 0, stream>>>(bsums, nblocks, avgp, out);
}

// Round 3
// 61.225 us; speedup vs baseline: 1.1054x; 1.0467x over previous
//
#include <hip/hip_runtime.h>

// SeesawLoss forward, N=32768 rows, C=1203 classes (+2 binary logits).
// Round 3: base-2 log domain (v_exp_f32 native), uniform label/binary loads
// (no per-element capture, 3 shuffle trees instead of 4+), label exclusion by
// subtraction, analytic LSE bound (skips the 4th reduction pass), P*log2(cum)
// table staged in LDS with 4 shift-replicated copies (aligned ds_read_b128
// for any row alignment), 4 rows per wave, 4 dispatches total.
// No float atomics (determinism).

#define C_CLS   1203
#define ROW_LEN 1205
#define NBINS   1204
#define PADLEN  1280
#define NEG_HUGE (-3.402823466e38f)
#define LOG2E    1.4426950408889634f
#define LN2      0.6931471805599453f
#define LOG_EPS2 (-6.643856189774724f)   // log2(0.01)
#define P_POW    0.8f
#define Q_POW    2.0f

#if __has_builtin(__builtin_amdgcn_exp2f)
#define EXP2(x) __builtin_amdgcn_exp2f(x)
#else
#define EXP2(x) exp2f(x)
#endif
#if __has_builtin(__builtin_amdgcn_logf)
#define LOG2F_(x) __builtin_amdgcn_logf(x)
#else
#define LOG2F_(x) __log2f(x)
#endif

__global__ void hist_k(const int* __restrict__ labels, unsigned* __restrict__ cum, int N) {
    int i = blockIdx.x * blockDim.x + threadIdx.x;
    int nv = N >> 2;
    const int4* lp = (const int4*)labels;
    if (i < nv) {
        int4 v = lp[i];
        atomicAdd(&cum[v.x], 1u);
        atomicAdd(&cum[v.y], 1u);
        atomicAdd(&cum[v.z], 1u);
        atomicAdd(&cum[v.w], 1u);
    }
    if (i < (N & 3)) atomicAdd(&cum[labels[(N & ~3) + i]], 1u);   // tail (block 0)
}

// One wave per row, 4 rows per wave (grid-stride). Row layout per lane:
// prefix [lane] if lane<k (k aligns row+k to 16B), then 5 float4 segments at
// element k + 256*i + 4*lane. Segments 0-3 are always pure classes
// (max idx k+1023 <= 1026 < 1203); only segment 4 needs masking.
__launch_bounds__(256)
__global__ void seesaw_row_k(const float* __restrict__ cls,
                             const int* __restrict__ labels,
                             const float* __restrict__ lweights,
                             const unsigned* __restrict__ cum,
                             float* __restrict__ bsums,
                             int N) {
    __shared__ __align__(16) float plg[4][PADLEN];   // plg[k][u] = P*log2(cum[u+k])
    __shared__ float bs[4];

    // ---- stage shift-replicated P*log2(count) table ----
    for (int u = threadIdx.x; u < PADLEN; u += 256) {
        #pragma unroll
        for (int kk = 0; kk < 4; ++kk) {
            int j = u + kk;
            float v = 0.0f;
            if (j < NBINS) {
                float c = fmaxf((float)cum[j], 1.0f);
                v = P_POW * LOG2F_(c);
            }
            plg[kk][u] = v;
        }
    }
    __syncthreads();

    const int lane   = threadIdx.x & 63;
    const int wv     = threadIdx.x >> 6;
    const int stride = gridDim.x * 4;
    float acc = 0.0f;

    for (int n = blockIdx.x * 4 + wv; n < N; n += stride) {
        const float* row  = cls + (size_t)n * ROW_LEN;
        const int   label = labels[n];
        const float w     = lweights[n];
        const int   k     = (-n) & 3;          // 1205 % 4 == 1

        // wave-uniform loads (issue early; row lines are being fetched anyway)
        const float labv = row[label];
        const float c0   = row[C_CLS];
        const float c1   = row[C_CLS + 1];

        // ---- vectorized row load ----
        const float4* vp = (const float4*)(row + k);
        float4 q[5];
        #pragma unroll
        for (int i = 0; i < 4; ++i) q[i] = vp[(size_t)i * 64 + lane];
        {
            int b4 = k + 1024 + 4 * lane;
            float4 t = make_float4(NEG_HUGE, NEG_HUGE, NEG_HUGE, NEG_HUGE);
            if (b4 + 3 <= C_CLS - 1) {
                t = vp[(size_t)256 + lane];
            } else {
                if (b4     <= C_CLS - 1) t.x = row[b4];
                if (b4 + 1 <= C_CLS - 1) t.y = row[b4 + 1];
                if (b4 + 2 <= C_CLS - 1) t.z = row[b4 + 2];
            }
            q[4] = t;
        }
        float pv2 = ((lane < k) ? row[lane] : NEG_HUGE) * LOG2E;

        // ---- to log2 domain + lane max ----
        float m = pv2;
        #pragma unroll
        for (int i = 0; i < 5; ++i) {
            q[i].x *= LOG2E; q[i].y *= LOG2E; q[i].z *= LOG2E; q[i].w *= LOG2E;
            m = fmaxf(m, fmaxf(fmaxf(q[i].x, q[i].y), fmaxf(q[i].z, q[i].w)));
        }
        #pragma unroll
        for (int o = 32; o > 0; o >>= 1) m = fmaxf(m, __shfl_xor(m, o, 64));

        // ---- softmax log2-denominator ----
        float s = EXP2(pv2 - m);
        #pragma unroll
        for (int i = 0; i < 5; ++i)
            s += EXP2(q[i].x - m) + EXP2(q[i].y - m)
               + EXP2(q[i].z - m) + EXP2(q[i].w - m);
        #pragma unroll
        for (int o = 32; o > 0; o >>= 1) s += __shfl_xor(s, o, 64);
        const float L2 = m + LOG2F_(s);

        const float labv2  = labv * LOG2E;
        const float logsm2 = fmaxf(labv2 - L2, LOG_EPS2);
        const float QLS2   = Q_POW * (L2 + logsm2);
        const float plogl  = plg[0][label];
        // analytic upper bound on adjusted logits (comp_j <= Q*(m-L-logsm))
        const float Ab2    = m + fmaxf(Q_POW * (m - L2 - logsm2), 0.0f);

        // ---- fused adjust + exp2 accumulate (label included; subtract after) ----
        float T;
        {
            float t1 = fminf(plg[0][lane] - plogl, 0.0f);
            float t2 = fmaxf(fmaf(Q_POW, pv2, -QLS2), 0.0f);
            T = EXP2((pv2 + t1 + t2) - Ab2);
        }
        #pragma unroll
        for (int i = 0; i < 5; ++i) {
            int u = 256 * i + 4 * lane;
            float4 lg = *(const float4*)&plg[k][u];
            float a;
            a = q[i].x + fminf(lg.x - plogl, 0.f) + fmaxf(fmaf(Q_POW, q[i].x, -QLS2), 0.f);
            T += EXP2(a - Ab2);
            a = q[i].y + fminf(lg.y - plogl, 0.f) + fmaxf(fmaf(Q_POW, q[i].y, -QLS2), 0.f);
            T += EXP2(a - Ab2);
            a = q[i].z + fminf(lg.z - plogl, 0.f) + fmaxf(fmaf(Q_POW, q[i].z, -QLS2), 0.f);
            T += EXP2(a - Ab2);
            a = q[i].w + fminf(lg.w - plogl, 0.f) + fmaxf(fmaf(Q_POW, q[i].w, -QLS2), 0.f);
            T += EXP2(a - Ab2);
        }
        #pragma unroll
        for (int o = 32; o > 0; o >>= 1) T += __shfl_xor(T, o, 64);

        // exclude the label term: adj[label] == csc[label] exactly
        T -= EXP2(labv2 - Ab2);

        // ---- per-row tail (uniform across lanes) ----
        const float nl2 = Ab2 + LOG2F_(T);          // neg_lse in log2
        const float xx  = (nl2 - labv2) * LN2;      // + pos_lse (= -labv), natural
        const float rl  = (xx > 0.0f) ? (xx + log1pf(__expf(-xx))) : log1pf(__expf(xx));

        const float mm   = fmaxf(c0, c1);
        const float lseb = mm + __logf(__expf(c0 - mm) + __expf(c1 - mm));
        const float ce   = lseb - ((label == C_CLS) ? c1 : c0);

        const float rlw = (w == 1.0f) ? rl : 0.0f;  // reference: pos_mask == 1.0
        acc += rlw + ce * w;
    }

    if (lane == 0) bs[wv] = acc;
    __syncthreads();
    if (threadIdx.x == 0)
        bsums[blockIdx.x] = (bs[0] + bs[1]) + (bs[2] + bs[3]);
}

__launch_bounds__(512)
__global__ void reduce_k(const float* __restrict__ bsums, int nb,
                         const int* __restrict__ avg_raw,
                         float* __restrict__ out) {
    int tid = threadIdx.x;
    float s = 0.0f;
    int nb4 = nb >> 2;
    const float4* bp = (const float4*)bsums;
    for (int i = tid; i < nb4; i += 512) {
        float4 v = bp[i];
        s += (v.x + v.y) + (v.z + v.w);
    }
    for (int i = (nb4 << 2) + tid; i < nb; i += 512) s += bsums[i];

    #pragma unroll
    for (int o = 32; o > 0; o >>= 1) s += __shfl_xor(s, o, 64);

    __shared__ float ws8[8];
    int lane = tid & 63, wvi = tid >> 6;
    if (lane == 0) ws8[wvi] = s;
    __syncthreads();
    if (tid == 0) {
        float t = 0.0f;
        #pragma unroll
        for (int i = 0; i < 8; ++i) t += ws8[i];
        int ai = avg_raw[0];
        float af;
        if (ai > 0 && ai < (1 << 26)) {
            af = (float)ai;              // stored as integer
        } else {
            union { int i; float f; } u; // stored as float bits
            u.i = ai;
            af = u.f;
        }
        out[0] = t / af;
    }
}

extern "C" void kernel_launch(void* const* d_in, const int* in_sizes, int n_in,
                              void* d_out, int out_size, void* d_ws, size_t ws_size,
                              hipStream_t stream) {
    const float* cls    = (const float*)d_in[0];
    const int*   labels = (const int*)d_in[1];
    const float* lw     = (const float*)d_in[2];
    const int*   avgp   = (const int*)d_in[3];
    float*       out    = (float*)d_out;

    const int N = in_sizes[1];

    // ws layout: [ unsigned cum[NBINS] (padded to 1280) | float bsums[grid] ]
    unsigned* cum   = (unsigned*)d_ws;
    float*    bsums = (float*)d_ws + 1280;

    int g = (N + 15) / 16;               // 4 waves/block * 4 rows/wave
    if (g > 2048) g = 2048;
    if (g < 1) g = 1;

    hipMemsetAsync(cum, 0, NBINS * sizeof(unsigned), stream);
    int hb = ((N >> 2) + 255) / 256;
    if (hb < 1) hb = 1;
    hist_k<<<hb, 256, 0, stream>>>(labels, cum, N);
    seesaw_row_k<<<g, 256, 0, stream>>>(cls, labels, lw, cum, bsums, N);
    reduce_k<<<1, 512, 0, stream>>>(bsums, g, avgp, out);
}